// Round 10
// baseline (694.306 us; speedup 1.0000x reference)
//
#include <hip/hip_runtime.h>
#include <math.h>
#include <stdint.h>

typedef __attribute__((ext_vector_type(8))) _Float16 h8;   // 8 f16 (4 VGPR) MFMA A/B frag
typedef __attribute__((ext_vector_type(4))) _Float16 h4v;  // 4 f16 (8B)
typedef __attribute__((ext_vector_type(4))) float f4;      // MFMA C/D frag

static constexpr int B_   = 32;
static constexpr int NV_  = 1024;
static constexpr int NC_  = 1024;
static constexpr int COL_ = 1038;
static constexpr int NF_  = 14;
static constexpr int E_   = 128;
static constexpr int ROWS_ = B_ * NV_;   // 32768

__device__ __forceinline__ _Float16 f2h(float f) { return (_Float16)f; }

// ---------------------------------------------------------------------------
// Cubic B-spline closed form (grid g[j] = (j-3)*0.4 - 1); cell c + 4 pieces.
// ---------------------------------------------------------------------------
__device__ __forceinline__ void bsp(float x, float& P0, float& P1, float& P2,
                                    float& P3, int& c) {
  float u = fmaf(x, 2.5f, 5.5f);
  float cf = floorf(u);
  c = (int)cf;
  float t = u - cf;
  float t2 = t * t, t3 = t2 * t;
  float omt = 1.f - t;
  P0 = t3 * (1.f / 6.f);
  P1 = fmaf(-3.f, t3, fmaf(3.f, t2, fmaf(3.f, t, 1.f))) * (1.f / 6.f);
  P2 = fmaf(3.f, t3, fmaf(-6.f, t2, 4.f)) * (1.f / 6.f);
  P3 = omt * omt * omt * (1.f / 6.f);
}
__device__ __forceinline__ float bsel(int p, float P0, float P1, float P2, float P3) {
  float v = 0.f;
  v = (p == 0) ? P0 : v; v = (p == 1) ? P1 : v;
  v = (p == 2) ? P2 : v; v = (p == 3) ? P3 : v;
  return v;
}

// ---------------------------------------------------------------------------
// Small prep kernels
// ---------------------------------------------------------------------------
__global__ void k_f32f16(const float* __restrict__ src, _Float16* __restrict__ dst, int n) {
  int idx = blockIdx.x * 256 + threadIdx.x;
  if (idx < n) dst[idx] = f2h(src[idx]);
}

// KAN weights -> [o=128][k=2048] f16, k = ch*16 + q (q=0 act, 1..8 spline, rest 0)
__global__ void k_pack16(const float* __restrict__ base, const float* __restrict__ spline,
                         const float* __restrict__ scaler, _Float16* __restrict__ W9t) {
  int idx = blockIdx.x * 256 + threadIdx.x;   // < 262144
  int o = idx >> 11, k = idx & 2047, ch = k >> 4, q = k & 15;
  float v = 0.f;
  if (q == 0) v = base[o * 128 + ch];
  else if (q <= 8) v = spline[(o * 128 + ch) * 8 + q - 1] * scaler[o * 128 + ch];
  W9t[idx] = f2h(v);
}

// kan3 (O=1) fp32 pack: w3[i*9+q]
__global__ void k_pack9k3(const float* __restrict__ base, const float* __restrict__ spline,
                          const float* __restrict__ scaler, float* __restrict__ w3) {
  int idx = blockIdx.x * 256 + threadIdx.x;
  if (idx >= 1152) return;
  int i = idx / 9, q = idx % 9;
  w3[idx] = (q == 0) ? base[i] : spline[i * 8 + q - 1] * scaler[i];
}

// ---------------------------------------------------------------------------
// Prep A: obs A-part fp32 -> A16[b][v][c] f16 AND AT16[b][c][v] f16.
// 64x64 tiles per block via LDS transpose. grid (16 ct, 16 vt, 32 b).
// ---------------------------------------------------------------------------
__global__ __launch_bounds__(256) void k_prepA(const float* __restrict__ obs,
                                               _Float16* __restrict__ A16,
                                               _Float16* __restrict__ AT16) {
  int ct = blockIdx.x, vt = blockIdx.y, b = blockIdx.z;
  __shared__ _Float16 tile[64][65];
  int t = threadIdx.x;
  int cl = t & 63, rq = t >> 6;
  const float* ob = obs + (size_t)b * NV_ * COL_ + NF_;
  _Float16* a16b = A16 + (size_t)b * NV_ * 1024;
#pragma unroll 4
  for (int r = 0; r < 16; ++r) {
    int vl = rq * 16 + r;
    int v = vt * 64 + vl, c = ct * 64 + cl;
    _Float16 h = f2h(ob[(size_t)v * COL_ + c]);
    a16b[(size_t)v * 1024 + c] = h;
    tile[vl][cl] = h;
  }
  __syncthreads();
  _Float16* at16b = AT16 + (size_t)b * NC_ * 1024;
#pragma unroll 4
  for (int r = 0; r < 16; ++r) {
    int crow = rq * 16 + r;
    at16b[(size_t)(ct * 64 + crow) * 1024 + vt * 64 + cl] = tile[cl][crow];
  }
}

// ---------------------------------------------------------------------------
// Embedding: X[row,e] = sum_f obs[row*COL_+f] * W_emb[e*14+f]
// ---------------------------------------------------------------------------
__global__ __launch_bounds__(256) void k_embed(const float* __restrict__ obs,
                                               const float* __restrict__ W_emb,
                                               float* __restrict__ X) {
  int t = threadIdx.x;
  int e = t & 127;
  size_t row = (size_t)blockIdx.x * 2 + (t >> 7);
  float w[NF_];
#pragma unroll
  for (int f = 0; f < NF_; ++f) w[f] = W_emb[e * NF_ + f];
  const float* orow = obs + row * COL_;
  float acc = 0.f;
#pragma unroll
  for (int f = 0; f < NF_; ++f) acc = fmaf(orow[f], w[f], acc);
  X[row * E_ + e] = acc;
}

// ---------------------------------------------------------------------------
// Transpose-convert X fp32 [b][v][128] -> f16 [b][e][1024] via LDS tiles.
// ---------------------------------------------------------------------------
__global__ __launch_bounds__(256) void k_transX(const float* __restrict__ Xf,
                                                _Float16* __restrict__ Xt) {
  int vt = blockIdx.x, et = blockIdx.y, b = blockIdx.z;
  __shared__ float tile[64][65];
  int t = threadIdx.x;
  int el = t & 63, q = t >> 6;
  const float* src = Xf + (size_t)b * 131072;
#pragma unroll 4
  for (int r = 0; r < 16; ++r) {
    int vl = q * 16 + r;
    tile[vl][el] = src[(size_t)(vt * 64 + vl) * 128 + et * 64 + el];
  }
  __syncthreads();
  _Float16* dst = Xt + (size_t)b * 131072;
#pragma unroll 4
  for (int r = 0; r < 16; ++r) {
    int el2 = q * 16 + r;
    dst[(size_t)(et * 64 + el2) * 1024 + vt * 64 + el] = f2h(tile[el][el2]);
  }
}

// ---------------------------------------------------------------------------
// Unified f16 GEMM for both einsums: out[b][r][e] = sum_k Ar[b][r][k]*Bt[b][e][k]
// Ar: f16 [b][1024][1024] (A16 or AT16), Bt: f16 [b][128][1024].
// grid 256 = 32b x 8 r-tiles; 4 waves 2x2, each 64x64.
// ---------------------------------------------------------------------------
__global__ __launch_bounds__(256) void k_einsum16(const _Float16* __restrict__ Ar,
                                                  const _Float16* __restrict__ Bt,
                                                  float* __restrict__ out) {
  int blk = blockIdx.x;
  int b = blk >> 3, rt = blk & 7;
  const _Float16* Arb = Ar + (size_t)b * 1024 * 1024;
  const _Float16* Btb = Bt + (size_t)b * 131072;
  float* outb = out + (size_t)b * 131072;
  int t = threadIdx.x, w = t >> 6, l = t & 63;
  int l15 = l & 15, g = l >> 4;
  int wR = (w >> 1) * 64, wC = (w & 1) * 64;
  int r0 = rt * 128;
  f4 acc[4][4] = {};

#pragma unroll 2
  for (int kk = 0; kk < 1024; kk += 32) {
    h8 af[4], bf[4];
#pragma unroll
    for (int m = 0; m < 4; ++m)
      af[m] = *(const h8*)(Arb + (size_t)(r0 + wR + m * 16 + l15) * 1024 + kk + g * 8);
#pragma unroll
    for (int n = 0; n < 4; ++n)
      bf[n] = *(const h8*)(Btb + (size_t)(wC + n * 16 + l15) * 1024 + kk + g * 8);
#pragma unroll
    for (int m = 0; m < 4; ++m)
#pragma unroll
      for (int n = 0; n < 4; ++n)
        acc[m][n] = __builtin_amdgcn_mfma_f32_16x16x32_f16(af[m], bf[n], acc[m][n], 0, 0, 0);
  }
#pragma unroll
  for (int m = 0; m < 4; ++m)
#pragma unroll
    for (int n = 0; n < 4; ++n)
#pragma unroll
      for (int rr = 0; rr < 4; ++rr)
        outb[(size_t)(r0 + wR + m * 16 + g * 4 + rr) * 128 + wC + n * 16 + l15] = acc[m][n][rr];
}

// ---------------------------------------------------------------------------
// Fallback einsums (fp32 A from obs, used only if ws too small for A16/AT16)
// ---------------------------------------------------------------------------
__global__ __launch_bounds__(256) void k_einsum_at(const float* __restrict__ obs,
                                                   const _Float16* __restrict__ Bt,
                                                   float* __restrict__ out) {
  int blk = blockIdx.x;
  int b = blk >> 3, ct = blk & 7;
  const float* obsb = obs + (size_t)b * NV_ * COL_;
  const _Float16* Btb = Bt + (size_t)b * 131072;
  float* outb = out + (size_t)b * 131072;
  int t = threadIdx.x, w = t >> 6, l = t & 63;
  int l15 = l & 15, g = l >> 4;
  int wR = (w >> 1) * 64, wC = (w & 1) * 64;
  int c0 = ct * 128;
  f4 acc[4][4] = {};
#pragma unroll 2
  for (int kk = 0; kk < NV_; kk += 32) {
    h8 af[4], bf[4];
#pragma unroll
    for (int m = 0; m < 4; ++m) {
      int c = c0 + wR + m * 16 + l15;
      const float* ap = obsb + (size_t)(kk + g * 8) * COL_ + NF_ + c;
#pragma unroll
      for (int j = 0; j < 8; ++j) af[m][j] = f2h(ap[(size_t)j * COL_]);
    }
#pragma unroll
    for (int n = 0; n < 4; ++n)
      bf[n] = *(const h8*)(Btb + (size_t)(wC + n * 16 + l15) * 1024 + kk + g * 8);
#pragma unroll
    for (int m = 0; m < 4; ++m)
#pragma unroll
      for (int n = 0; n < 4; ++n)
        acc[m][n] = __builtin_amdgcn_mfma_f32_16x16x32_f16(af[m], bf[n], acc[m][n], 0, 0, 0);
  }
#pragma unroll
  for (int m = 0; m < 4; ++m)
#pragma unroll
    for (int n = 0; n < 4; ++n)
#pragma unroll
      for (int rr = 0; rr < 4; ++rr)
        outb[(size_t)(c0 + wR + m * 16 + g * 4 + rr) * 128 + wC + n * 16 + l15] = acc[m][n][rr];
}

__global__ __launch_bounds__(256) void k_einsum_a(const float* __restrict__ obs,
                                                  const _Float16* __restrict__ Bt,
                                                  float* __restrict__ out) {
  int blk = blockIdx.x;
  int b = blk >> 3, vt = blk & 7;
  const float* obsb = obs + (size_t)b * NV_ * COL_;
  const _Float16* Btb = Bt + (size_t)b * 131072;
  float* outb = out + (size_t)b * 131072;
  int t = threadIdx.x, w = t >> 6, l = t & 63;
  int l15 = l & 15, g = l >> 4;
  int wR = (w >> 1) * 64, wC = (w & 1) * 64;
  int v0 = vt * 128;
  f4 acc[4][4] = {};
#pragma unroll 2
  for (int kk = 0; kk < NC_; kk += 32) {
    h8 af[4], bf[4];
#pragma unroll
    for (int m = 0; m < 4; ++m) {
      int v = v0 + wR + m * 16 + l15;
      const float2* ap = (const float2*)(obsb + (size_t)v * COL_ + NF_ + kk + g * 8);
      float2 p0 = ap[0], p1 = ap[1], p2 = ap[2], p3 = ap[3];
      af[m][0] = f2h(p0.x); af[m][1] = f2h(p0.y);
      af[m][2] = f2h(p1.x); af[m][3] = f2h(p1.y);
      af[m][4] = f2h(p2.x); af[m][5] = f2h(p2.y);
      af[m][6] = f2h(p3.x); af[m][7] = f2h(p3.y);
    }
#pragma unroll
    for (int n = 0; n < 4; ++n)
      bf[n] = *(const h8*)(Btb + (size_t)(wC + n * 16 + l15) * 1024 + kk + g * 8);
#pragma unroll
    for (int m = 0; m < 4; ++m)
#pragma unroll
      for (int n = 0; n < 4; ++n)
        acc[m][n] = __builtin_amdgcn_mfma_f32_16x16x32_f16(af[m], bf[n], acc[m][n], 0, 0, 0);
  }
#pragma unroll
  for (int m = 0; m < 4; ++m)
#pragma unroll
    for (int n = 0; n < 4; ++n)
#pragma unroll
      for (int rr = 0; rr < 4; ++rr)
        outb[(size_t)(v0 + wR + m * 16 + g * 4 + rr) * 128 + wC + n * 16 + l15] = acc[m][n][rr];
}

// ---------------------------------------------------------------------------
// Linear (MFMA): outT[b][o][row_in_batch] f16 = In@W^T + bias
// ---------------------------------------------------------------------------
__global__ __launch_bounds__(256) void k_lin(const _Float16* __restrict__ Inb,
                                             const _Float16* __restrict__ Wb,
                                             const float* __restrict__ bias,
                                             _Float16* __restrict__ outT) {
  int row0 = blockIdx.x * 128;
  int b = row0 >> 10, vb = row0 & 1023;
  int t = threadIdx.x, w = t >> 6, l = t & 63;
  int l15 = l & 15, g = l >> 4;
  int wR = (w >> 1) * 64, wC = (w & 1) * 64;
  f4 acc[4][4] = {};

#pragma unroll
  for (int kk = 0; kk < 128; kk += 32) {
    h8 af[4], bf[4];
#pragma unroll
    for (int m = 0; m < 4; ++m)
      af[m] = *(const h8*)(Inb + (size_t)(row0 + wR + m * 16 + l15) * 128 + kk + g * 8);
#pragma unroll
    for (int n = 0; n < 4; ++n)
      bf[n] = *(const h8*)(Wb + (size_t)(wC + n * 16 + l15) * 128 + kk + g * 8);
#pragma unroll
    for (int m = 0; m < 4; ++m)
#pragma unroll
      for (int n = 0; n < 4; ++n)
        acc[m][n] = __builtin_amdgcn_mfma_f32_16x16x32_f16(af[m], bf[n], acc[m][n], 0, 0, 0);
  }
#pragma unroll
  for (int m = 0; m < 4; ++m)
#pragma unroll
    for (int n = 0; n < 4; ++n) {
      int col = wC + n * 16 + l15;
      float bv = bias[col];
      h4v sv;
#pragma unroll
      for (int rr = 0; rr < 4; ++rr) sv[rr] = f2h(acc[m][n][rr] + bv);
      *(h4v*)(outT + (size_t)b * 131072 + (size_t)col * 1024 + vb + wR + m * 16 + g * 4) = sv;
    }
}

// ---------------------------------------------------------------------------
// Fused LN + tanh + optional residual; writes fp32 AND f16.
// ---------------------------------------------------------------------------
__global__ __launch_bounds__(256) void k_ln(const float* in, const float* gam,
                                            const float* bet, const float* addp,
                                            float* outf, _Float16* outb) {
  size_t wid = ((size_t)blockIdx.x * 256 + threadIdx.x) >> 6;
  int lane = threadIdx.x & 63;
  const float* r = in + wid * E_;
  float x0 = r[lane], x1 = r[lane + 64];
  float s = x0 + x1;
  float s2 = x0 * x0 + x1 * x1;
#pragma unroll
  for (int off = 32; off >= 1; off >>= 1) {
    s += __shfl_xor(s, off);
    s2 += __shfl_xor(s2, off);
  }
  float mu = s * (1.0f / 128.0f);
  float var = s2 * (1.0f / 128.0f) - mu * mu;
  float rstd = rsqrtf(var + 1e-5f);
  float t0 = tanhf((x0 - mu) * rstd * gam[lane] + bet[lane]);
  float t1 = tanhf((x1 - mu) * rstd * gam[lane + 64] + bet[lane + 64]);
  if (addp) {
    t0 += addp[wid * E_ + lane];
    t1 += addp[wid * E_ + lane + 64];
  }
  outf[wid * E_ + lane] = t0;
  outf[wid * E_ + lane + 64] = t1;
  outb[wid * E_ + lane] = f2h(t0);
  outb[wid * E_ + lane + 64] = f2h(t1);
}

// ---------------------------------------------------------------------------
// Fused KAN (o=128, MFMA): f16 input, f16 output. Bases closed-form into
// XOR-swizzled LDS. LDS: xs 34.8KB + As 16KB = 51KB -> 3 blocks/CU.
// ---------------------------------------------------------------------------
template <int ACT>
__global__ __launch_bounds__(256) void k_kan(const _Float16* __restrict__ Xin,
                                             const _Float16* __restrict__ W9t,
                                             _Float16* __restrict__ out) {
  int row0 = blockIdx.x * 128;
  __shared__ _Float16 xs[128 * 136];
  __shared__ _Float16 As[128 * 64];   // [row][4ch*16] f16, 128B rows, XOR-swizzled
  int t = threadIdx.x, w = t >> 6, l = t & 63;
  int l15 = l & 15, g = l >> 4;
  int wR = (w >> 1) * 64, wC = (w & 1) * 64;
  int rr_ = t & 127, sub = t >> 7;

  // stage x-tile (vector f16 loads, 8-wide)
#pragma unroll
  for (int p = 0; p < 8; ++p) {
    int idx8 = (p * 256 + t) * 8;
    int r = idx8 >> 7, c8 = idx8 & 127;
    *(h8*)(&xs[r * 136 + c8]) = *(const h8*)(Xin + (size_t)(row0 + r) * 128 + c8);
  }
  __syncthreads();

  f4 acc[4][4] = {};
  for (int chunk = 0; chunk < 32; ++chunk) {
#pragma unroll
    for (int s = 0; s < 2; ++s) {
      int cl = sub * 2 + s;            // 0..3
      int ch = chunk * 4 + cl;
      float x = (float)xs[rr_ * 136 + ch];
      float act;
      if (ACT == 0) act = x / (1.f + __expf(-x));
      else          act = 1.f / (1.f + __expf(-x));
      float P0, P1, P2, P3; int c;
      bsp(x, P0, P1, P2, P3, c);
      h8 lo, hi;
      lo[0] = f2h(act);
#pragma unroll
      for (int j = 0; j < 7; ++j) lo[1 + j] = f2h(bsel(c - j, P0, P1, P2, P3));
      hi[0] = f2h(bsel(c - 7, P0, P1, P2, P3));
#pragma unroll
      for (int q = 1; q < 8; ++q) hi[q] = (_Float16)0.f;
      int sw = (rr_ & 7) << 4;
      *(h8*)((char*)As + rr_ * 128 + ((cl * 32) ^ sw)) = lo;
      *(h8*)((char*)As + rr_ * 128 + ((cl * 32 + 16) ^ sw)) = hi;
    }
    __syncthreads();
#pragma unroll
    for (int ks = 0; ks < 2; ++ks) {
      h8 af[4], bf[4];
#pragma unroll
      for (int m = 0; m < 4; ++m) {
        int r = wR + m * 16 + l15;
        int cb = (ks * 64 + g * 16) ^ ((r & 7) << 4);
        af[m] = *(h8*)((char*)As + r * 128 + cb);
      }
#pragma unroll
      for (int n = 0; n < 4; ++n) {
        int col = wC + n * 16 + l15;
        bf[n] = *(const h8*)(W9t + (size_t)col * 2048 + chunk * 64 + ks * 32 + g * 8);
      }
#pragma unroll
      for (int m = 0; m < 4; ++m)
#pragma unroll
        for (int n = 0; n < 4; ++n)
          acc[m][n] = __builtin_amdgcn_mfma_f32_16x16x32_f16(af[m], bf[n], acc[m][n], 0, 0, 0);
    }
    __syncthreads();
  }
#pragma unroll
  for (int m = 0; m < 4; ++m)
#pragma unroll
    for (int n = 0; n < 4; ++n)
#pragma unroll
      for (int rr = 0; rr < 4; ++rr)
        out[(size_t)(row0 + wR + m * 16 + g * 4 + rr) * 128 + wC + n * 16 + l15] =
            f2h(acc[m][n][rr]);
}

// ---------------------------------------------------------------------------
// KAN3 (o=1, fp32 math, f16 input) + final affine. One wave per row.
// ---------------------------------------------------------------------------
__global__ __launch_bounds__(256) void k_kan3(const _Float16* __restrict__ xin,
                                              const float* __restrict__ w3,
                                              float* __restrict__ out) {
  size_t wid = ((size_t)blockIdx.x * 256 + threadIdx.x) >> 6;
  int lane = threadIdx.x & 63;
  const _Float16* xr = xin + wid * E_;
  float s = 0.f;
#pragma unroll
  for (int half = 0; half < 2; ++half) {
    int i = lane + half * 64;
    float x = (float)xr[i];
    float sig = 1.f / (1.f + __expf(-x));
    const float* ww = w3 + i * 9;
    s = fmaf(sig, ww[0], s);
    float P0, P1, P2, P3; int c;
    bsp(x, P0, P1, P2, P3, c);
#pragma unroll
    for (int j = 0; j < 8; ++j) s = fmaf(bsel(c - j, P0, P1, P2, P3), ww[1 + j], s);
  }
#pragma unroll
  for (int off = 32; off >= 1; off >>= 1) s += __shfl_xor(s, off);
  if (lane == 0) out[wid] = s * 0.6f + 0.2f;
}

// ---------------------------------------------------------------------------
extern "C" void kernel_launch(void* const* d_in, const int* in_sizes, int n_in,
                              void* d_out, int out_size, void* d_ws, size_t ws_size,
                              hipStream_t stream) {
  (void)in_sizes; (void)n_in; (void)out_size;
  const float* obs   = (const float*)d_in[0];
  const float* W_emb = (const float*)d_in[1];
  const float* ln1_g = (const float*)d_in[2];
  const float* ln1_b = (const float*)d_in[3];
  const float* ln2_g = (const float*)d_in[4];
  const float* ln2_b = (const float*)d_in[5];
  const float* ln3_g = (const float*)d_in[6];
  const float* ln3_b = (const float*)d_in[7];
  const float* ln4_g = (const float*)d_in[8];
  const float* ln4_b = (const float*)d_in[9];
  const float* lin1_w = (const float*)d_in[10];
  const float* lin1_b = (const float*)d_in[11];
  const float* lin2_w = (const float*)d_in[12];
  const float* lin2_b = (const float*)d_in[13];
  const float* lin3_w = (const float*)d_in[14];
  const float* lin3_b = (const float*)d_in[15];
  const float* kan1_base = (const float*)d_in[16];
  const float* kan1_spline = (const float*)d_in[17];
  const float* kan1_scaler = (const float*)d_in[18];
  const float* kan2_base = (const float*)d_in[19];
  const float* kan2_spline = (const float*)d_in[20];
  const float* kan2_scaler = (const float*)d_in[21];
  const float* kan3_base = (const float*)d_in[22];
  const float* kan3_spline = (const float*)d_in[23];
  const float* kan3_scaler = (const float*)d_in[24];

  char* wsb = (char*)d_ws;
  const size_t MB16 = (size_t)1 << 24;
  const size_t MB8  = (size_t)1 << 23;
  float* Xf  = (float*)(wsb);
  float* XCC = (float*)(wsb + MB16);
  float* XCV = (float*)(wsb + 2 * MB16);
  float* T1  = (float*)(wsb + 3 * MB16);
  _Float16* LTt = (_Float16*)(wsb + 4 * MB16);          // 8MB
  _Float16* LNb = (_Float16*)(wsb + 4 * MB16 + MB8);    // 8MB
  char*  p   = wsb + 4 * MB16 + 2 * MB8;
  _Float16* W9t1 = (_Float16*)p;      p += 128 * 2048 * 2;
  _Float16* W9t2 = (_Float16*)p;      p += 128 * 2048 * 2;
  _Float16* Wb1  = (_Float16*)p;      p += 128 * 128 * 2;
  _Float16* Wb2  = (_Float16*)p;      p += 128 * 128 * 2;
  _Float16* Wb3  = (_Float16*)p;      p += 128 * 128 * 2;
  float* w3v  = (float*)p;            p += 1152 * 4;
  p = (char*)(((uintptr_t)p + 255) & ~(uintptr_t)255);
  _Float16* A16  = (_Float16*)p;                       // 64MB
  _Float16* AT16 = (_Float16*)(p + (size_t)NV_ * 1024 * 2 * B_);
  size_t need = (size_t)(p - wsb) + 2 * (size_t)B_ * NV_ * 1024 * 2;
  const bool fast = ws_size >= need;

  // weight prep
  k_f32f16<<<64, 256, 0, stream>>>(lin1_w, Wb1, 16384);
  k_f32f16<<<64, 256, 0, stream>>>(lin2_w, Wb2, 16384);
  k_f32f16<<<64, 256, 0, stream>>>(lin3_w, Wb3, 16384);
  k_pack16<<<1024, 256, 0, stream>>>(kan1_base, kan1_spline, kan1_scaler, W9t1);
  k_pack16<<<1024, 256, 0, stream>>>(kan2_base, kan2_spline, kan2_scaler, W9t2);
  k_pack9k3<<<5, 256, 0, stream>>>(kan3_base, kan3_spline, kan3_scaler, w3v);
  if (fast) k_prepA<<<dim3(16, 16, 32), 256, 0, stream>>>(obs, A16, AT16);

  // 1. X = embed(obs); Xt = transpose(X) f16
  k_embed<<<ROWS_ / 2, 256, 0, stream>>>(obs, W_emb, Xf);
  k_transX<<<dim3(16, 2, 32), 256, 0, stream>>>(Xf, LTt);
  // 2. T1 = A^T X
  if (fast) k_einsum16<<<256, 256, 0, stream>>>(AT16, LTt, T1);
  else      k_einsum_at<<<256, 256, 0, stream>>>(obs, LTt, T1);
  // 3. XCC = tanh(LN1(T1))
  k_ln<<<ROWS_ / 4, 256, 0, stream>>>(T1, ln1_g, ln1_b, nullptr, XCC, LNb);
  // 4. LTt = (XCC @ W1^T + b1)^T f16
  k_lin<<<256, 256, 0, stream>>>(LNb, Wb1, lin1_b, LTt);
  // 5. T1 = A @ lin1out
  if (fast) k_einsum16<<<256, 256, 0, stream>>>(A16, LTt, T1);
  else      k_einsum_a<<<256, 256, 0, stream>>>(obs, LTt, T1);
  // 6. XCV = tanh(LN2(T1)) + X
  k_ln<<<ROWS_ / 4, 256, 0, stream>>>(T1, ln2_g, ln2_b, Xf, XCV, LNb);
  // 7. lin2
  k_lin<<<256, 256, 0, stream>>>(LNb, Wb2, lin2_b, LTt);
  // 8. T1 = A^T lin2out
  if (fast) k_einsum16<<<256, 256, 0, stream>>>(AT16, LTt, T1);
  else      k_einsum_at<<<256, 256, 0, stream>>>(obs, LTt, T1);
  // 9. tanh(LN3(T1)) + XCC
  k_ln<<<ROWS_ / 4, 256, 0, stream>>>(T1, ln3_g, ln3_b, XCC, XCC, LNb);
  // 10. lin3
  k_lin<<<256, 256, 0, stream>>>(LNb, Wb3, lin3_b, LTt);
  // 11. T1 = A @ lin3out
  if (fast) k_einsum16<<<256, 256, 0, stream>>>(A16, LTt, T1);
  else      k_einsum_a<<<256, 256, 0, stream>>>(obs, LTt, T1);
  // 12. LNb := f16(tanh(LN4(T1)) + XCV)   (KAN input; XCC f32 copy unused)
  k_ln<<<ROWS_ / 4, 256, 0, stream>>>(T1, ln4_g, ln4_b, XCV, XCC, LNb);
  // 13. LTt = KAN1(LNb) f16  (LTt free after step 11)
  k_kan<0><<<256, 256, 0, stream>>>(LNb, W9t1, LTt);
  // 14. LNb = KAN2(LTt) f16
  k_kan<0><<<256, 256, 0, stream>>>(LTt, W9t2, LNb);
  // 15. out = KAN3(LNb) * 0.6 + 0.2
  k_kan3<<<ROWS_ / 4, 256, 0, stream>>>(LNb, w3v, (float*)d_out);
}

// Round 13
// 689.154 us; speedup vs baseline: 1.0075x; 1.0075x over previous
//
#include <hip/hip_runtime.h>
#include <math.h>
#include <stdint.h>

typedef __attribute__((ext_vector_type(8))) _Float16 h8;   // 8 f16 (4 VGPR) MFMA A/B frag
typedef __attribute__((ext_vector_type(4))) _Float16 h4v;  // 4 f16 (8B)
typedef __attribute__((ext_vector_type(4))) float f4;      // MFMA C/D frag

static constexpr int B_   = 32;
static constexpr int NV_  = 1024;
static constexpr int NC_  = 1024;
static constexpr int COL_ = 1038;
static constexpr int NF_  = 14;
static constexpr int E_   = 128;
static constexpr int ROWS_ = B_ * NV_;   // 32768

__device__ __forceinline__ _Float16 f2h(float f) { return (_Float16)f; }

// ---------------------------------------------------------------------------
// Cubic B-spline closed form (grid g[j] = (j-3)*0.4 - 1); cell c + 4 pieces.
// ---------------------------------------------------------------------------
__device__ __forceinline__ void bsp(float x, float& P0, float& P1, float& P2,
                                    float& P3, int& c) {
  float u = fmaf(x, 2.5f, 5.5f);
  float cf = floorf(u);
  c = (int)cf;
  float t = u - cf;
  float t2 = t * t, t3 = t2 * t;
  float omt = 1.f - t;
  P0 = t3 * (1.f / 6.f);
  P1 = fmaf(-3.f, t3, fmaf(3.f, t2, fmaf(3.f, t, 1.f))) * (1.f / 6.f);
  P2 = fmaf(3.f, t3, fmaf(-6.f, t2, 4.f)) * (1.f / 6.f);
  P3 = omt * omt * omt * (1.f / 6.f);
}
__device__ __forceinline__ float bsel(int p, float P0, float P1, float P2, float P3) {
  float v = 0.f;
  v = (p == 0) ? P0 : v; v = (p == 1) ? P1 : v;
  v = (p == 2) ? P2 : v; v = (p == 3) ? P3 : v;
  return v;
}

// ---------------------------------------------------------------------------
// Small prep kernels
// ---------------------------------------------------------------------------
__global__ void k_f32f16(const float* __restrict__ src, _Float16* __restrict__ dst, int n) {
  int idx = blockIdx.x * 256 + threadIdx.x;
  if (idx < n) dst[idx] = f2h(src[idx]);
}

// KAN weights -> [o=128][k=2048] f16, k = ch*16 + q (q=0 act, 1..8 spline, rest 0)
__global__ void k_pack16(const float* __restrict__ base, const float* __restrict__ spline,
                         const float* __restrict__ scaler, _Float16* __restrict__ W9t) {
  int idx = blockIdx.x * 256 + threadIdx.x;   // < 262144
  int o = idx >> 11, k = idx & 2047, ch = k >> 4, q = k & 15;
  float v = 0.f;
  if (q == 0) v = base[o * 128 + ch];
  else if (q <= 8) v = spline[(o * 128 + ch) * 8 + q - 1] * scaler[o * 128 + ch];
  W9t[idx] = f2h(v);
}

// kan3 (O=1) fp32 pack: w3[i*9+q]
__global__ void k_pack9k3(const float* __restrict__ base, const float* __restrict__ spline,
                          const float* __restrict__ scaler, float* __restrict__ w3) {
  int idx = blockIdx.x * 256 + threadIdx.x;
  if (idx >= 1152) return;
  int i = idx / 9, q = idx % 9;
  w3[idx] = (q == 0) ? base[i] : spline[i * 8 + q - 1] * scaler[i];
}

// ---------------------------------------------------------------------------
// Embedding: X[row,e] = sum_f obs[row*COL_+f] * W_emb[e*14+f]
// ---------------------------------------------------------------------------
__global__ __launch_bounds__(256) void k_embed(const float* __restrict__ obs,
                                               const float* __restrict__ W_emb,
                                               float* __restrict__ X) {
  int t = threadIdx.x;
  int e = t & 127;
  size_t row = (size_t)blockIdx.x * 2 + (t >> 7);
  float w[NF_];
#pragma unroll
  for (int f = 0; f < NF_; ++f) w[f] = W_emb[e * NF_ + f];
  const float* orow = obs + row * COL_;
  float acc = 0.f;
#pragma unroll
  for (int f = 0; f < NF_; ++f) acc = fmaf(orow[f], w[f], acc);
  X[row * E_ + e] = acc;
}

// ---------------------------------------------------------------------------
// Transpose-convert X fp32 [b][v][128] -> f16 [b][e][1024] via LDS tiles.
// ---------------------------------------------------------------------------
__global__ __launch_bounds__(256) void k_transX(const float* __restrict__ Xf,
                                                _Float16* __restrict__ Xt) {
  int vt = blockIdx.x, et = blockIdx.y, b = blockIdx.z;
  __shared__ float tile[64][65];
  int t = threadIdx.x;
  int el = t & 63, q = t >> 6;
  const float* src = Xf + (size_t)b * 131072;
#pragma unroll 4
  for (int r = 0; r < 16; ++r) {
    int vl = q * 16 + r;
    tile[vl][el] = src[(size_t)(vt * 64 + vl) * 128 + et * 64 + el];
  }
  __syncthreads();
  _Float16* dst = Xt + (size_t)b * 131072;
#pragma unroll 4
  for (int r = 0; r < 16; ++r) {
    int el2 = q * 16 + r;
    dst[(size_t)(et * 64 + el2) * 1024 + vt * 64 + el] = f2h(tile[el][el2]);
  }
}

// ---------------------------------------------------------------------------
// einsum 'bvc,bve->bce': out[b,c,e] = sum_v A[b,v,c]*X[b,v,e]. 64x64 tiles,
// grid 1024 (32b x 16 mt x 2 nt) -> 4 blocks/CU, 4 waves/SIMD.
// A: strided fp32 from obs + cvt (16-lane x 64B coalesced). B: f16 [b][e][v].
// ---------------------------------------------------------------------------
__global__ __launch_bounds__(256) void k_einsum_at(const float* __restrict__ obs,
                                                   const _Float16* __restrict__ Bt,
                                                   float* __restrict__ out) {
  int blk = blockIdx.x;
  int b = blk >> 5, rest = blk & 31;
  int mt = rest >> 1, nt = rest & 1;
  const float* obsb = obs + (size_t)b * NV_ * COL_;
  const _Float16* Btb = Bt + (size_t)b * 131072;
  float* outb = out + (size_t)b * 131072;
  int t = threadIdx.x, w = t >> 6, l = t & 63;
  int l15 = l & 15, g = l >> 4;
  int wm = w >> 1, wn = w & 1;
  int c0 = mt * 64 + wm * 32;
  int e0 = nt * 64 + wn * 32;
  f4 acc[2][2] = {};

#pragma unroll 2
  for (int kk = 0; kk < NV_; kk += 32) {
    h8 af[2], bf[2];
#pragma unroll
    for (int m = 0; m < 2; ++m) {
      int c = c0 + m * 16 + l15;
      const float* ap = obsb + (size_t)(kk + g * 8) * COL_ + NF_ + c;
#pragma unroll
      for (int j = 0; j < 8; ++j) af[m][j] = f2h(ap[(size_t)j * COL_]);
    }
#pragma unroll
    for (int n = 0; n < 2; ++n)
      bf[n] = *(const h8*)(Btb + (size_t)(e0 + n * 16 + l15) * 1024 + kk + g * 8);
#pragma unroll
    for (int m = 0; m < 2; ++m)
#pragma unroll
      for (int n = 0; n < 2; ++n)
        acc[m][n] = __builtin_amdgcn_mfma_f32_16x16x32_f16(af[m], bf[n], acc[m][n], 0, 0, 0);
  }
#pragma unroll
  for (int m = 0; m < 2; ++m)
#pragma unroll
    for (int n = 0; n < 2; ++n)
#pragma unroll
      for (int rr = 0; rr < 4; ++rr)
        outb[(size_t)(c0 + m * 16 + g * 4 + rr) * 128 + e0 + n * 16 + l15] = acc[m][n][rr];
}

// ---------------------------------------------------------------------------
// einsum 'bvc,bce->bve': out[b,v,e] = sum_c A[b,v,c]*Y[b,c,e]. 64x64 tiles,
// grid 1024. A: contiguous fp32 (float2 x4) + cvt. B: f16 [b][e][c].
// ---------------------------------------------------------------------------
__global__ __launch_bounds__(256) void k_einsum_a(const float* __restrict__ obs,
                                                  const _Float16* __restrict__ Bt,
                                                  float* __restrict__ out) {
  int blk = blockIdx.x;
  int b = blk >> 5, rest = blk & 31;
  int mt = rest >> 1, nt = rest & 1;
  const float* obsb = obs + (size_t)b * NV_ * COL_;
  const _Float16* Btb = Bt + (size_t)b * 131072;
  float* outb = out + (size_t)b * 131072;
  int t = threadIdx.x, w = t >> 6, l = t & 63;
  int l15 = l & 15, g = l >> 4;
  int wm = w >> 1, wn = w & 1;
  int v0 = mt * 64 + wm * 32;
  int e0 = nt * 64 + wn * 32;
  f4 acc[2][2] = {};

#pragma unroll 2
  for (int kk = 0; kk < NC_; kk += 32) {
    h8 af[2], bf[2];
#pragma unroll
    for (int m = 0; m < 2; ++m) {
      int v = v0 + m * 16 + l15;
      const float2* ap = (const float2*)(obsb + (size_t)v * COL_ + NF_ + kk + g * 8);
      float2 p0 = ap[0], p1 = ap[1], p2 = ap[2], p3 = ap[3];
      af[m][0] = f2h(p0.x); af[m][1] = f2h(p0.y);
      af[m][2] = f2h(p1.x); af[m][3] = f2h(p1.y);
      af[m][4] = f2h(p2.x); af[m][5] = f2h(p2.y);
      af[m][6] = f2h(p3.x); af[m][7] = f2h(p3.y);
    }
#pragma unroll
    for (int n = 0; n < 2; ++n)
      bf[n] = *(const h8*)(Btb + (size_t)(e0 + n * 16 + l15) * 1024 + kk + g * 8);
#pragma unroll
    for (int m = 0; m < 2; ++m)
#pragma unroll
      for (int n = 0; n < 2; ++n)
        acc[m][n] = __builtin_amdgcn_mfma_f32_16x16x32_f16(af[m], bf[n], acc[m][n], 0, 0, 0);
  }
#pragma unroll
  for (int m = 0; m < 2; ++m)
#pragma unroll
    for (int n = 0; n < 2; ++n)
#pragma unroll
      for (int rr = 0; rr < 4; ++rr)
        outb[(size_t)(v0 + m * 16 + g * 4 + rr) * 128 + e0 + n * 16 + l15] = acc[m][n][rr];
}

// ---------------------------------------------------------------------------
// Linear (MFMA): outT[b][o][row_in_batch] f16 = In@W^T + bias
// ---------------------------------------------------------------------------
__global__ __launch_bounds__(256) void k_lin(const _Float16* __restrict__ Inb,
                                             const _Float16* __restrict__ Wb,
                                             const float* __restrict__ bias,
                                             _Float16* __restrict__ outT) {
  int row0 = blockIdx.x * 128;
  int b = row0 >> 10, vb = row0 & 1023;
  int t = threadIdx.x, w = t >> 6, l = t & 63;
  int l15 = l & 15, g = l >> 4;
  int wR = (w >> 1) * 64, wC = (w & 1) * 64;
  f4 acc[4][4] = {};

#pragma unroll
  for (int kk = 0; kk < 128; kk += 32) {
    h8 af[4], bf[4];
#pragma unroll
    for (int m = 0; m < 4; ++m)
      af[m] = *(const h8*)(Inb + (size_t)(row0 + wR + m * 16 + l15) * 128 + kk + g * 8);
#pragma unroll
    for (int n = 0; n < 4; ++n)
      bf[n] = *(const h8*)(Wb + (size_t)(wC + n * 16 + l15) * 128 + kk + g * 8);
#pragma unroll
    for (int m = 0; m < 4; ++m)
#pragma unroll
      for (int n = 0; n < 4; ++n)
        acc[m][n] = __builtin_amdgcn_mfma_f32_16x16x32_f16(af[m], bf[n], acc[m][n], 0, 0, 0);
  }
#pragma unroll
  for (int m = 0; m < 4; ++m)
#pragma unroll
    for (int n = 0; n < 4; ++n) {
      int col = wC + n * 16 + l15;
      float bv = bias[col];
      h4v sv;
#pragma unroll
      for (int rr = 0; rr < 4; ++rr) sv[rr] = f2h(acc[m][n][rr] + bv);
      *(h4v*)(outT + (size_t)b * 131072 + (size_t)col * 1024 + vb + wR + m * 16 + g * 4) = sv;
    }
}

// ---------------------------------------------------------------------------
// Fused LN + tanh + optional residual; writes fp32 (nullable) AND f16.
// ---------------------------------------------------------------------------
__global__ __launch_bounds__(256) void k_ln(const float* in, const float* gam,
                                            const float* bet, const float* addp,
                                            float* outf, _Float16* outb) {
  size_t wid = ((size_t)blockIdx.x * 256 + threadIdx.x) >> 6;
  int lane = threadIdx.x & 63;
  const float* r = in + wid * E_;
  float x0 = r[lane], x1 = r[lane + 64];
  float s = x0 + x1;
  float s2 = x0 * x0 + x1 * x1;
#pragma unroll
  for (int off = 32; off >= 1; off >>= 1) {
    s += __shfl_xor(s, off);
    s2 += __shfl_xor(s2, off);
  }
  float mu = s * (1.0f / 128.0f);
  float var = s2 * (1.0f / 128.0f) - mu * mu;
  float rstd = rsqrtf(var + 1e-5f);
  float t0 = tanhf((x0 - mu) * rstd * gam[lane] + bet[lane]);
  float t1 = tanhf((x1 - mu) * rstd * gam[lane + 64] + bet[lane + 64]);
  if (addp) {
    t0 += addp[wid * E_ + lane];
    t1 += addp[wid * E_ + lane + 64];
  }
  if (outf) {
    outf[wid * E_ + lane] = t0;
    outf[wid * E_ + lane + 64] = t1;
  }
  outb[wid * E_ + lane] = f2h(t0);
  outb[wid * E_ + lane + 64] = f2h(t1);
}

// ---------------------------------------------------------------------------
// Fused KAN (o=128, MFMA): f16 in/out. 64-row tiles, grid 512 -> 2 blocks/CU.
// 4 waves each own a 32-col slice; spline bases computed once per block into
// XOR-swizzled LDS (row stride 256B; byte ^= (row&7)<<4).
// LDS: xs 17KB + As 16KB = 33KB.
// ---------------------------------------------------------------------------
template <int ACT>
__global__ __launch_bounds__(256) void k_kan(const _Float16* __restrict__ Xin,
                                             const _Float16* __restrict__ W9t,
                                             _Float16* __restrict__ out) {
  int row0 = blockIdx.x * 64;
  __shared__ _Float16 xs[64 * 136];
  __shared__ _Float16 As[64 * 128];   // [row][8ch*16] f16, 256B rows, swizzled
  int t = threadIdx.x, w = t >> 6, l = t & 63;
  int l15 = l & 15, g = l >> 4;
  int rr_ = t & 63, sub = t >> 6;

  // stage x-tile (vector f16 loads)
#pragma unroll
  for (int p = 0; p < 4; ++p) {
    int idx8 = (p * 256 + t) * 8;
    int r = idx8 >> 7, c8 = idx8 & 127;
    *(h8*)(&xs[r * 136 + c8]) = *(const h8*)(Xin + (size_t)(row0 + r) * 128 + c8);
  }
  __syncthreads();

  f4 acc[4][2] = {};
  for (int chunk = 0; chunk < 16; ++chunk) {
#pragma unroll
    for (int s = 0; s < 2; ++s) {
      int cl = sub * 2 + s;            // 0..7
      int ch = chunk * 8 + cl;
      float x = (float)xs[rr_ * 136 + ch];
      float act;
      if (ACT == 0) act = x / (1.f + __expf(-x));
      else          act = 1.f / (1.f + __expf(-x));
      float P0, P1, P2, P3; int c;
      bsp(x, P0, P1, P2, P3, c);
      h8 lo, hi;
      lo[0] = f2h(act);
#pragma unroll
      for (int j = 0; j < 7; ++j) lo[1 + j] = f2h(bsel(c - j, P0, P1, P2, P3));
      hi[0] = f2h(bsel(c - 7, P0, P1, P2, P3));
#pragma unroll
      for (int q = 1; q < 8; ++q) hi[q] = (_Float16)0.f;
      int sw = (rr_ & 7) << 4;
      *(h8*)((char*)As + rr_ * 256 + ((cl * 32) ^ sw)) = lo;
      *(h8*)((char*)As + rr_ * 256 + ((cl * 32 + 16) ^ sw)) = hi;
    }
    __syncthreads();
#pragma unroll
    for (int ks = 0; ks < 4; ++ks) {
      h8 af[4], bf[2];
#pragma unroll
      for (int m = 0; m < 4; ++m) {
        int r = m * 16 + l15;
        int cb = (ks * 64 + g * 16) ^ ((r & 7) << 4);
        af[m] = *(h8*)((char*)As + r * 256 + cb);
      }
#pragma unroll
      for (int n = 0; n < 2; ++n) {
        int col = w * 32 + n * 16 + l15;
        bf[n] = *(const h8*)(W9t + (size_t)col * 2048 + chunk * 128 + ks * 32 + g * 8);
      }
#pragma unroll
      for (int m = 0; m < 4; ++m)
#pragma unroll
        for (int n = 0; n < 2; ++n)
          acc[m][n] = __builtin_amdgcn_mfma_f32_16x16x32_f16(af[m], bf[n], acc[m][n], 0, 0, 0);
    }
    __syncthreads();
  }
#pragma unroll
  for (int m = 0; m < 4; ++m)
#pragma unroll
    for (int n = 0; n < 2; ++n)
#pragma unroll
      for (int rr = 0; rr < 4; ++rr)
        out[(size_t)(row0 + m * 16 + g * 4 + rr) * 128 + w * 32 + n * 16 + l15] =
            f2h(acc[m][n][rr]);
}

// ---------------------------------------------------------------------------
// KAN3 (o=1, fp32 math, f16 input) + final affine. One wave per row.
// ---------------------------------------------------------------------------
__global__ __launch_bounds__(256) void k_kan3(const _Float16* __restrict__ xin,
                                              const float* __restrict__ w3,
                                              float* __restrict__ out) {
  size_t wid = ((size_t)blockIdx.x * 256 + threadIdx.x) >> 6;
  int lane = threadIdx.x & 63;
  const _Float16* xr = xin + wid * E_;
  float s = 0.f;
#pragma unroll
  for (int half = 0; half < 2; ++half) {
    int i = lane + half * 64;
    float x = (float)xr[i];
    float sig = 1.f / (1.f + __expf(-x));
    const float* ww = w3 + i * 9;
    s = fmaf(sig, ww[0], s);
    float P0, P1, P2, P3; int c;
    bsp(x, P0, P1, P2, P3, c);
#pragma unroll
    for (int j = 0; j < 8; ++j) s = fmaf(bsel(c - j, P0, P1, P2, P3), ww[1 + j], s);
  }
#pragma unroll
  for (int off = 32; off >= 1; off >>= 1) s += __shfl_xor(s, off);
  if (lane == 0) out[wid] = s * 0.6f + 0.2f;
}

// ---------------------------------------------------------------------------
extern "C" void kernel_launch(void* const* d_in, const int* in_sizes, int n_in,
                              void* d_out, int out_size, void* d_ws, size_t ws_size,
                              hipStream_t stream) {
  (void)in_sizes; (void)n_in; (void)out_size; (void)ws_size;
  const float* obs   = (const float*)d_in[0];
  const float* W_emb = (const float*)d_in[1];
  const float* ln1_g = (const float*)d_in[2];
  const float* ln1_b = (const float*)d_in[3];
  const float* ln2_g = (const float*)d_in[4];
  const float* ln2_b = (const float*)d_in[5];
  const float* ln3_g = (const float*)d_in[6];
  const float* ln3_b = (const float*)d_in[7];
  const float* ln4_g = (const float*)d_in[8];
  const float* ln4_b = (const float*)d_in[9];
  const float* lin1_w = (const float*)d_in[10];
  const float* lin1_b = (const float*)d_in[11];
  const float* lin2_w = (const float*)d_in[12];
  const float* lin2_b = (const float*)d_in[13];
  const float* lin3_w = (const float*)d_in[14];
  const float* lin3_b = (const float*)d_in[15];
  const float* kan1_base = (const float*)d_in[16];
  const float* kan1_spline = (const float*)d_in[17];
  const float* kan1_scaler = (const float*)d_in[18];
  const float* kan2_base = (const float*)d_in[19];
  const float* kan2_spline = (const float*)d_in[20];
  const float* kan2_scaler = (const float*)d_in[21];
  const float* kan3_base = (const float*)d_in[22];
  const float* kan3_spline = (const float*)d_in[23];
  const float* kan3_scaler = (const float*)d_in[24];

  char* wsb = (char*)d_ws;
  const size_t MB16 = (size_t)1 << 24;
  const size_t MB8  = (size_t)1 << 23;
  float* Xf  = (float*)(wsb);
  float* XCC = (float*)(wsb + MB16);
  float* XCV = (float*)(wsb + 2 * MB16);
  float* T1  = (float*)(wsb + 3 * MB16);
  _Float16* LTt = (_Float16*)(wsb + 4 * MB16);          // 8MB
  _Float16* LNb = (_Float16*)(wsb + 4 * MB16 + MB8);    // 8MB
  char*  p   = wsb + 4 * MB16 + 2 * MB8;
  _Float16* W9t1 = (_Float16*)p;      p += 128 * 2048 * 2;
  _Float16* W9t2 = (_Float16*)p;      p += 128 * 2048 * 2;
  _Float16* Wb1  = (_Float16*)p;      p += 128 * 128 * 2;
  _Float16* Wb2  = (_Float16*)p;      p += 128 * 128 * 2;
  _Float16* Wb3  = (_Float16*)p;      p += 128 * 128 * 2;
  float* w3v  = (float*)p;

  // weight prep
  k_f32f16<<<64, 256, 0, stream>>>(lin1_w, Wb1, 16384);
  k_f32f16<<<64, 256, 0, stream>>>(lin2_w, Wb2, 16384);
  k_f32f16<<<64, 256, 0, stream>>>(lin3_w, Wb3, 16384);
  k_pack16<<<1024, 256, 0, stream>>>(kan1_base, kan1_spline, kan1_scaler, W9t1);
  k_pack16<<<1024, 256, 0, stream>>>(kan2_base, kan2_spline, kan2_scaler, W9t2);
  k_pack9k3<<<5, 256, 0, stream>>>(kan3_base, kan3_spline, kan3_scaler, w3v);

  // 1. X = embed(obs); Xt = transpose(X) f16
  k_embed<<<ROWS_ / 2, 256, 0, stream>>>(obs, W_emb, Xf);
  k_transX<<<dim3(16, 2, 32), 256, 0, stream>>>(Xf, LTt);
  // 2. T1 = A^T X
  k_einsum_at<<<1024, 256, 0, stream>>>(obs, LTt, T1);
  // 3. XCC = tanh(LN1(T1))
  k_ln<<<ROWS_ / 4, 256, 0, stream>>>(T1, ln1_g, ln1_b, nullptr, XCC, LNb);
  // 4. LTt = (XCC @ W1^T + b1)^T f16
  k_lin<<<256, 256, 0, stream>>>(LNb, Wb1, lin1_b, LTt);
  // 5. T1 = A @ lin1out
  k_einsum_a<<<1024, 256, 0, stream>>>(obs, LTt, T1);
  // 6. XCV = tanh(LN2(T1)) + X
  k_ln<<<ROWS_ / 4, 256, 0, stream>>>(T1, ln2_g, ln2_b, Xf, XCV, LNb);
  // 7. lin2
  k_lin<<<256, 256, 0, stream>>>(LNb, Wb2, lin2_b, LTt);
  // 8. T1 = A^T lin2out
  k_einsum_at<<<1024, 256, 0, stream>>>(obs, LTt, T1);
  // 9. f16(tanh(LN3(T1)) + XCC) -> LNb   (fp32 copy dead -> skipped)
  k_ln<<<ROWS_ / 4, 256, 0, stream>>>(T1, ln3_g, ln3_b, XCC, nullptr, LNb);
  // 10. lin3
  k_lin<<<256, 256, 0, stream>>>(LNb, Wb3, lin3_b, LTt);
  // 11. T1 = A @ lin3out
  k_einsum_a<<<1024, 256, 0, stream>>>(obs, LTt, T1);
  // 12. LNb := f16(tanh(LN4(T1)) + XCV)   (fp32 copy dead -> skipped)
  k_ln<<<ROWS_ / 4, 256, 0, stream>>>(T1, ln4_g, ln4_b, XCV, nullptr, LNb);
  // 13. LTt = KAN1(LNb) f16
  k_kan<0><<<512, 256, 0, stream>>>(LNb, W9t1, LTt);
  // 14. LNb = KAN2(LTt) f16
  k_kan<0><<<512, 256, 0, stream>>>(LTt, W9t2, LNb);
  // 15. out = KAN3(LNb) * 0.6 + 0.2
  k_kan3<<<ROWS_ / 4, 256, 0, stream>>>(LNb, w3v, (float*)d_out);
}